// Round 14
// baseline (135.485 us; speedup 1.0000x reference)
//
#include <hip/hip_runtime.h>
#include <cmath>

typedef __bf16 bf16x4v __attribute__((ext_vector_type(4)));
typedef __bf16 bf16x8 __attribute__((ext_vector_type(8)));
typedef float f32x4 __attribute__((ext_vector_type(4)));

namespace {
constexpr int kN = 16, kC = 64, kT = 512, kV = 25, kS = 3, kO = 64;
constexpr int kTV = kT * kV;  // 12800
// ws bytes: xm f32 | afrag[48][8192][16] | w3f[3][512][16] | x_tr bf16 | psum
constexpr size_t WS_AFRAG = 102400;
constexpr size_t WS_W3F = WS_AFRAG + (size_t)48 * 131072;   // 6,393,856
constexpr size_t WS_XTR = WS_W3F + 3 * 8192;                // 6,418,432
constexpr size_t WS_PSUM = WS_XTR + (size_t)16 * 819200 * 2 + 4096;  // 32,636,928 (4KB OOB pad)
}  // namespace

// X3s: bf16 [c 64][t 16][u 32], XOR bits 4-6 only. Bytes [0, 65536).
// Wave w owns rows c in [16w, 16w+16) -> entirely wave-local (no barriers).
__device__ __forceinline__ int swzC(int c, int t, int ubyte) {
  return (c << 10) + (((t << 6) + ubyte) ^ ((((c ^ t) & 7)) << 4));
}

// ---- k1: x f32 -> x_tr bf16 [n][t][u25][c64] (LDS transpose) + mean partials
__global__ __launch_bounds__(512) void k1_tr(const float* __restrict__ x,
                                             unsigned char* __restrict__ ws) {
  const int n = blockIdx.x, tc = blockIdx.y;  // 32-t chunks
  extern __shared__ __align__(16) unsigned char sm1[];  // 102400: bf16 [64][800]
  __bf16* tile = (__bf16*)sm1;
  const int tid = threadIdx.x;
  const float4* xg4 = (const float4*)(x + (size_t)n * kC * kTV);
  for (int i4 = tid; i4 < 12800; i4 += 512) {
    int c = i4 / 200, r = i4 % 200;
    float4 v = xg4[c * 3200 + tc * 200 + r];
    bf16x4v o;
    o[0] = (__bf16)v.x; o[1] = (__bf16)v.y;
    o[2] = (__bf16)v.z; o[3] = (__bf16)v.w;
    *(bf16x4v*)(tile + c * 800 + r * 4) = o;
  }
  __syncthreads();
  // transpose out: col=(t_loc*25+u) -> x_tr[...][col][c], c-contiguous b128s
  __bf16* xtr = (__bf16*)(ws + WS_XTR) + (size_t)n * 819200 + (size_t)tc * 51200;
  for (int col = tid; col < 800; col += 512) {
    __bf16* dst = xtr + (size_t)col * 64;
#pragma unroll
    for (int cb = 0; cb < 8; ++cb) {
      bf16x8 pk;
#pragma unroll
      for (int j = 0; j < 8; ++j) pk[j] = tile[(cb * 8 + j) * 800 + col];
      *(bf16x8*)(dst + cb * 8) = pk;
    }
  }
  // mean partials over this chunk's 32 t
  float* psum = (float*)(ws + WS_PSUM);
  for (int i = tid; i < 1600; i += 512) {
    int c = i / 25, v = i % 25;
    float s = 0.f;
#pragma unroll
    for (int t = 0; t < 32; ++t) s += (float)tile[c * 800 + t * 25 + v];
    psum[((size_t)n * 1600 + i) * 16 + tc] = s;
  }
}

// ---- k1b: xm = sum(psum)/512
__global__ __launch_bounds__(256) void k1_red(const unsigned char* __restrict__ ws_c,
                                              float* __restrict__ xm) {
  const float* psum = (const float*)(ws_c + WS_PSUM);
  const int n = blockIdx.x, tid = threadIdx.x;
  for (int i = tid; i < 1600; i += 256) {
    const float4* p = (const float4*)(psum + ((size_t)n * 1600 + i) * 16);
    float s = 0.f;
#pragma unroll
    for (int q = 0; q < 4; ++q) {
      float4 v = p[q];
      s += v.x + v.y + v.z + v.w;
    }
    xm[n * 1600 + i] = s * (1.f / 512.f);
  }
}

// ---- k2: a_frag (bf16, MFMA-B order, bias/colsum folded) + w3 frags
__global__ __launch_bounds__(256) void k2_attn(
    const float* __restrict__ xm, const float* __restrict__ Ag,
    const float* __restrict__ alpha, const float* __restrict__ w1,
    const float* __restrict__ b1, const float* __restrict__ w2,
    const float* __restrict__ b2, const float* __restrict__ w3,
    const float* __restrict__ w4, const float* __restrict__ b4,
    const int* __restrict__ sparse, unsigned char* __restrict__ ws) {
  const float thr = (float)sparse[0];
  const int b = blockIdx.x;
  const int s = b >> 6, n = (b >> 2) & 15, q = b & 3;
  __shared__ float xm_l[1600];
  __shared__ float x1_l[200], x2_l[200];
  __shared__ float att_l[8 * 625];
  __shared__ float attsum_l[200];
  __shared__ float ag_l[625];
  __shared__ float acs_l[25];
  __shared__ float w4_l[512];
  const int tid = threadIdx.x;
  for (int i = tid; i < 1600; i += 256) xm_l[i] = xm[n * 1600 + i];
  for (int i = tid; i < 512; i += 256) {
    float w = w4[s * 512 + i];
    w4_l[i] = (fabsf(w) > thr) ? w : 0.f;
  }
  for (int i = tid; i < 625; i += 256) ag_l[i] = Ag[s * 625 + i];
  __syncthreads();
  for (int i = tid; i < 400; i += 256) {
    int which = i / 200, idx = i % 200, r = idx / 25, u = idx % 25;
    const float* wrow = (which == 0 ? w1 : w2) + (s * 8 + r) * 64;
    float acc = 0.f;
    for (int cc = 0; cc < 64; ++cc) {
      float w = wrow[cc];
      w = (fabsf(w) > thr) ? w : 0.f;
      acc += w * xm_l[cc * 25 + u];
    }
    acc += (which == 0 ? b1 : b2)[s * 8 + r];
    if (which == 0) x1_l[idx] = acc;
    else x2_l[idx] = acc;
  }
  __syncthreads();
  for (int i = tid; i < 8 * 625; i += 256) {
    int r = i / 625, uv = i % 625, u = uv / 25, v = uv % 25;
    att_l[i] = tanhf(x1_l[r * 25 + u] - x2_l[r * 25 + v]);
  }
  __syncthreads();
  if (tid < 200) {
    int r = tid / 25, v = tid % 25;
    float sum = 0.f;
    for (int u = 0; u < 25; ++u) sum += att_l[r * 625 + u * 25 + v];
    attsum_l[tid] = sum;
  } else if (tid < 225) {
    int v = tid - 200;
    float sum = 0.f;
    for (int u = 0; u < 25; ++u) sum += ag_l[u * 25 + v];
    acs_l[v] = sum;
  }
  __syncthreads();
  const float al = alpha[0];
  // a_ext[c][u][v]: u<25 -> a ; u==25 -> colsum(a) (bias-fold) ; u>25 -> 0
  unsigned char* afrag = ws + WS_AFRAG + (size_t)(s * 16 + n) * 131072;
  for (int slot = q * 2048 + tid; slot < (q + 1) * 2048; slot += 256) {
    int c = slot >> 7, vt = (slot >> 6) & 1, l = slot & 63;
    int v = vt * 16 + (l & 15), g = l >> 4;
    bf16x8 out;
    if (v < 25) {
      float b4v = b4[s * 64 + c];
#pragma unroll
      for (int j = 0; j < 8; ++j) {
        int u = g * 8 + j;
        float val = 0.f;
        if (u < 25) {
          float acc = 0.f;
#pragma unroll
          for (int r = 0; r < 8; ++r) acc += w4_l[c * 8 + r] * att_l[r * 625 + u * 25 + v];
          val = al * (acc + b4v) + ag_l[u * 25 + v];
        } else if (u == 25) {
          float acc = 0.f;
#pragma unroll
          for (int r = 0; r < 8; ++r) acc += w4_l[c * 8 + r] * attsum_l[r * 25 + v];
          val = al * acc + 25.f * al * b4v + acs_l[v];
        }
        out[j] = (__bf16)val;
      }
    } else {
#pragma unroll
      for (int j = 0; j < 8; ++j) out[j] = (__bf16)0.f;
    }
    *(bf16x8*)(afrag + (size_t)slot * 16) = out;
  }
  // w3 frags (B-operand layout [o][c'])
  if (n == 0 && tid < 128) {
    unsigned char* w3f = ws + WS_W3F + (size_t)s * 8192;
    int slot = q * 128 + tid;
    int ot = slot >> 7, ks = (slot >> 6) & 1, l = slot & 63;
    int o = ot * 16 + (l & 15), g = l >> 4;
    bf16x8 out;
#pragma unroll
    for (int j = 0; j < 8; ++j) {
      int cp = ks * 32 + g * 8 + j;
      float w = w3[(s * 64 + o) * 64 + cp];
      out[j] = (__bf16)((fabsf(w) > thr) ? w : 0.f);
    }
    *(bf16x8*)(w3f + slot * 16) = out;
  }
}

// ---- k3: BARRIER-FREE. Wave = 16 channels x 16 t. GEMM1->X3s->GEMM2 wave-local.
__global__ __launch_bounds__(256) void k3_main(const float* __restrict__ x,
                                               const __bf16* __restrict__ xtr,
                                               const float* __restrict__ b3,
                                               const unsigned char* __restrict__ ws,
                                               float* __restrict__ y) {
  const int n = blockIdx.x;   // linear%8 == n%8 -> same-n blocks share XCD
  const int tb = blockIdx.y;  // 0..31 (16-t chunks)
  extern __shared__ __align__(16) unsigned char smem[];  // 65536
  const int tid = threadIdx.x;
  const int w = tid >> 6, l = tid & 63, g = l >> 4, l15 = l & 15;
  const int co = w * 16;

  // per-wave: zero own X3s pads u=26..31 (wave-local ordering suffices)
  for (int idx = l; idx < 768; idx += 64) {
    int pair = idx / 3, k = idx % 3;
    int cl = pair >> 4, t = pair & 15;
    *(unsigned int*)(smem + swzC(co + cl, t, 52 + 4 * k)) = 0u;
  }

  // prologue preloads: w3 frags for all 3 s (ot = w), b3 scalars
  const unsigned char* w3f = ws + WS_W3F;
  bf16x8 wk00 = *(const bf16x8*)(w3f + 0 * 8192 + ((w * 2 + 0) * 64 + l) * 16);
  bf16x8 wk01 = *(const bf16x8*)(w3f + 0 * 8192 + ((w * 2 + 1) * 64 + l) * 16);
  bf16x8 wk10 = *(const bf16x8*)(w3f + 1 * 8192 + ((w * 2 + 0) * 64 + l) * 16);
  bf16x8 wk11 = *(const bf16x8*)(w3f + 1 * 8192 + ((w * 2 + 1) * 64 + l) * 16);
  bf16x8 wk20 = *(const bf16x8*)(w3f + 2 * 8192 + ((w * 2 + 0) * 64 + l) * 16);
  bf16x8 wk21 = *(const bf16x8*)(w3f + 2 * 8192 + ((w * 2 + 1) * 64 + l) * 16);
  float b3v0 = b3[0 * 64 + co + (l & 15)];
  float b3v1 = b3[1 * 64 + co + (l & 15)];
  float b3v2 = b3[2 * 64 + co + (l & 15)];

  const __bf16* xt = xtr + (size_t)n * 819200 + (size_t)tb * 400 * 64;
  const unsigned char* afrag = ws + WS_AFRAG;

  f32x4 zacc[16][2];
#pragma unroll
  for (int cc = 0; cc < 16; ++cc)
#pragma unroll
    for (int vt = 0; vt < 2; ++vt) {
      f32x4 zz = {0.f, 0.f, 0.f, 0.f};
      zacc[cc][vt] = zz;
    }

#pragma unroll
  for (int s = 0; s < kS; ++s) {
    const bf16x8 wks0 = (s == 0) ? wk00 : (s == 1) ? wk10 : wk20;
    const bf16x8 wks1 = (s == 0) ? wk01 : (s == 1) ? wk11 : wk21;
    const float b3vs = (s == 0) ? b3v0 : (s == 1) ? b3v1 : b3v2;
    // GEMM1: 16 t, 4 b128 xa loads + 4 MFMA each, scatter to own X3s rows
#pragma unroll
    for (int t = 0; t < 16; ++t) {
      const __bf16* bp = xt + (size_t)t * 1600;  // (t*25)*64
      bf16x8 xa00 = *(const bf16x8*)(bp + l15 * 64 + g * 8);
      bf16x8 xa01 = *(const bf16x8*)(bp + l15 * 64 + 32 + g * 8);
      bf16x8 xa10 = *(const bf16x8*)(bp + (16 + l15) * 64 + g * 8);
      bf16x8 xa11 = *(const bf16x8*)(bp + (16 + l15) * 64 + 32 + g * 8);
      f32x4 d0 = {0.f, 0.f, 0.f, 0.f}, d1 = {0.f, 0.f, 0.f, 0.f};
      d0 = __builtin_amdgcn_mfma_f32_16x16x32_bf16(xa00, wks0, d0, 0, 0, 0);
      d0 = __builtin_amdgcn_mfma_f32_16x16x32_bf16(xa01, wks1, d0, 0, 0, 0);
      d1 = __builtin_amdgcn_mfma_f32_16x16x32_bf16(xa10, wks0, d1, 0, 0, 0);
      d1 = __builtin_amdgcn_mfma_f32_16x16x32_bf16(xa11, wks1, d1, 0, 0, 0);
      int c = co + l15;
      {
        bf16x4v pk;
        pk[0] = (__bf16)d0[0]; pk[1] = (__bf16)d0[1];
        pk[2] = (__bf16)d0[2]; pk[3] = (__bf16)d0[3];
        *(bf16x4v*)(smem + swzC(c, t, g * 8)) = pk;
      }
      if (g < 2) {
        bf16x4v pk;
        pk[0] = (__bf16)d1[0]; pk[1] = (__bf16)d1[1];
        pk[2] = (__bf16)d1[2]; pk[3] = (__bf16)d1[3];
        *(bf16x4v*)(smem + swzC(c, t, 32 + g * 8)) = pk;
      } else if (g == 2) {
        *(__bf16*)(smem + swzC(c, t, 48)) = (__bf16)d1[0];
      }
    }
    // bias row u=25 (own rows)
#pragma unroll
    for (int k = 0; k < 4; ++k)
      *(__bf16*)(smem + swzC(co + (l & 15), (l >> 4) + 4 * k, 50)) = (__bf16)b3vs;
    // GEMM2 with 2-channel-ahead B2 pipeline (wave-local LDS reads)
    const unsigned char* af = afrag + (size_t)(s * 16 + n) * 131072;
    bf16x8 cur0 = *(const bf16x8*)(af + ((co * 2 + 0) * 64 + l) * 16);
    bf16x8 cur1 = *(const bf16x8*)(af + ((co * 2 + 1) * 64 + l) * 16);
    bf16x8 nxt0 = *(const bf16x8*)(af + (((co + 1) * 2 + 0) * 64 + l) * 16);
    bf16x8 nxt1 = *(const bf16x8*)(af + (((co + 1) * 2 + 1) * 64 + l) * 16);
#pragma unroll
    for (int cc = 0; cc < 16; ++cc) {
      bf16x8 f0, f1;
      if (cc < 14) {
        f0 = *(const bf16x8*)(af + (((co + cc + 2) * 2 + 0) * 64 + l) * 16);
        f1 = *(const bf16x8*)(af + (((co + cc + 2) * 2 + 1) * 64 + l) * 16);
      }
      bf16x8 a2 = *(const bf16x8*)(smem + swzC(co + cc, l15, g * 16));
      zacc[cc][0] = __builtin_amdgcn_mfma_f32_16x16x32_bf16(a2, cur0, zacc[cc][0], 0, 0, 0);
      zacc[cc][1] = __builtin_amdgcn_mfma_f32_16x16x32_bf16(a2, cur1, zacc[cc][1], 0, 0, 0);
      if (cc < 14) {
        cur0 = nxt0; cur1 = nxt1;
        nxt0 = f0; nxt1 = f1;
      } else {
        cur0 = nxt0; cur1 = nxt1;
      }
    }
  }

  // epilogue (wave-local, no barrier): zs overlays own X3s region, 2 halves
  float* zs = (float*)(smem + w * 16384);
  const float4* xg4 = (const float4*)(x + (size_t)n * kC * kTV);
  float4* yg4 = (float4*)(y + (size_t)n * kC * kTV);
#pragma unroll
  for (int hh = 0; hh < 2; ++hh) {
#pragma unroll
    for (int cc = 0; cc < 8; ++cc) {
#pragma unroll
      for (int vt = 0; vt < 2; ++vt) {
        int v = vt * 16 + l15;
        if (v < 25) {
#pragma unroll
          for (int jj = 0; jj < 4; ++jj)
            zs[cc * 400 + (g * 4 + jj) * 25 + v] = zacc[hh * 8 + cc][vt][jj];
        }
      }
    }
    for (int i4 = l; i4 < 800; i4 += 64) {
      int ccl = i4 / 100, r4 = i4 % 100;
      int cg = co + hh * 8 + ccl;
      f32x4 zv = *(const f32x4*)(zs + ccl * 400 + r4 * 4);
      float4 xv = xg4[cg * 3200 + tb * 100 + r4];
      float4 o;
      o.x = fmaxf(zv[0] + xv.x, 0.f);
      o.y = fmaxf(zv[1] + xv.y, 0.f);
      o.z = fmaxf(zv[2] + xv.z, 0.f);
      o.w = fmaxf(zv[3] + xv.w, 0.f);
      yg4[cg * 3200 + tb * 100 + r4] = o;
    }
  }
}

extern "C" void kernel_launch(void* const* d_in, const int* in_sizes, int n_in,
                              void* d_out, int out_size, void* d_ws, size_t ws_size,
                              hipStream_t stream) {
  const float* x = (const float*)d_in[0];
  const float* Ag = (const float*)d_in[1];
  const float* alpha = (const float*)d_in[2];
  const float* w1 = (const float*)d_in[3];
  const float* b1 = (const float*)d_in[4];
  const float* w2 = (const float*)d_in[5];
  const float* b2 = (const float*)d_in[6];
  const float* w3 = (const float*)d_in[7];
  const float* b3 = (const float*)d_in[8];
  const float* w4 = (const float*)d_in[9];
  const float* b4 = (const float*)d_in[10];
  const int* sparse = (const int*)d_in[11];

  unsigned char* ws = (unsigned char*)d_ws;
  float* xm = (float*)ws;  // [16][64][25] f32 at offset 0
  const __bf16* xtr = (const __bf16*)(ws + WS_XTR);
  float* y = (float*)d_out;

  hipFuncSetAttribute((const void*)k1_tr,
                      hipFuncAttributeMaxDynamicSharedMemorySize, 102400);
  hipFuncSetAttribute((const void*)k3_main,
                      hipFuncAttributeMaxDynamicSharedMemorySize, 65536);

  dim3 g1(kN, kT / 32);
  k1_tr<<<g1, 512, 102400, stream>>>(x, ws);
  k1_red<<<kN, 256, 0, stream>>>(ws, xm);
  k2_attn<<<kS * kN * 4, 256, 0, stream>>>(xm, Ag, alpha, w1, b1, w2, b2, w3, w4,
                                           b4, sparse, ws);
  dim3 g3(kN, kT / 16);
  k3_main<<<g3, 256, 65536, stream>>>(x, (const __bf16*)xtr, b3, ws, y);
}

// Round 15
// 86.409 us; speedup vs baseline: 1.5679x; 1.5679x over previous
//
#include <hip/hip_runtime.h>
#include <cmath>

typedef __bf16 bf16x4v __attribute__((ext_vector_type(4)));
typedef __bf16 bf16x8 __attribute__((ext_vector_type(8)));
typedef float f32x4 __attribute__((ext_vector_type(4)));

namespace {
constexpr int kN = 16, kC = 64, kT = 512, kV = 25, kS = 3, kO = 64;
constexpr int kTV = kT * kV;  // 12800
// ws bytes: (unused 102400) | afrag[48][8192][16] | w3f[3][512][16] | x_tr | psum
constexpr size_t WS_AFRAG = 102400;
constexpr size_t WS_W3F = WS_AFRAG + (size_t)48 * 131072;   // 6,393,856
constexpr size_t WS_XTR = WS_W3F + 3 * 8192;                // 6,418,432
constexpr size_t WS_PSUM = WS_XTR + (size_t)16 * 819200 * 2 + 4096;  // 32,641,024
}  // namespace

// X3s: bf16 [c 64][t 16][u 32], XOR bits 4-6 only (>= 16B read granule).
// Bytes [0, 65536). w3_lds at [65536, 90112).
__device__ __forceinline__ int swzB16(int c, int t, int ubyte) {
  return (c << 10) + (((t << 6) + ubyte) ^ ((((c ^ t) & 7)) << 4));
}

// ---- k1: x f32 -> x_tr bf16 [n][tc][col=(t32*25+u)][c64] + mean partials
__global__ __launch_bounds__(512) void k1_tr(const float* __restrict__ x,
                                             unsigned char* __restrict__ ws) {
  const int n = blockIdx.x, tc = blockIdx.y;  // 16 x 16 (32-t chunks)
  extern __shared__ __align__(16) unsigned char sm1[];  // 102400: bf16 [64][800]
  __bf16* tile = (__bf16*)sm1;
  const int tid = threadIdx.x;
  const float4* xg4 = (const float4*)(x + (size_t)n * kC * kTV);
  for (int i4 = tid; i4 < 12800; i4 += 512) {
    int c = i4 / 200, r = i4 % 200;
    float4 v = xg4[c * 3200 + tc * 200 + r];
    bf16x4v o;
    o[0] = (__bf16)v.x; o[1] = (__bf16)v.y;
    o[2] = (__bf16)v.z; o[3] = (__bf16)v.w;
    *(bf16x4v*)(tile + c * 800 + r * 4) = o;
  }
  __syncthreads();
  // transpose out: col -> x_tr[...][col][c], c-contiguous b128 stores
  __bf16* xtr = (__bf16*)(ws + WS_XTR) + (size_t)n * 819200 + (size_t)tc * 51200;
  for (int col = tid; col < 800; col += 512) {
    __bf16* dst = xtr + (size_t)col * 64;
#pragma unroll
    for (int cb = 0; cb < 8; ++cb) {
      bf16x8 pk;
#pragma unroll
      for (int j = 0; j < 8; ++j) pk[j] = tile[(cb * 8 + j) * 800 + col];
      *(bf16x8*)(dst + cb * 8) = pk;
    }
  }
  // mean partials over this chunk's 32 t
  float* psum = (float*)(ws + WS_PSUM);
  for (int i = tid; i < 1600; i += 512) {
    int c = i / 25, v = i % 25;
    float s = 0.f;
#pragma unroll
    for (int t = 0; t < 32; ++t) s += (float)tile[c * 800 + t * 25 + v];
    psum[((size_t)n * 1600 + i) * 16 + tc] = s;
  }
}

// ---- k2: a_frag (bf16, MFMA-B order, bias/colsum folded) + w3 frags
// (xm reduced inline from psum)
__global__ __launch_bounds__(256) void k2_attn(
    const float* __restrict__ Ag, const float* __restrict__ alpha,
    const float* __restrict__ w1, const float* __restrict__ b1,
    const float* __restrict__ w2, const float* __restrict__ b2,
    const float* __restrict__ w3, const float* __restrict__ w4,
    const float* __restrict__ b4, const int* __restrict__ sparse,
    unsigned char* __restrict__ ws) {
  const float thr = (float)sparse[0];
  const int b = blockIdx.x;
  const int s = b >> 6, n = (b >> 2) & 15, q = b & 3;
  __shared__ float xm_l[1600];
  __shared__ float x1_l[200], x2_l[200];
  __shared__ float att_l[8 * 625];
  __shared__ float attsum_l[200];
  __shared__ float ag_l[625];
  __shared__ float acs_l[25];
  __shared__ float w4_l[512];
  const int tid = threadIdx.x;
  const float* psum = (const float*)(ws + WS_PSUM);
  for (int i = tid; i < 1600; i += 256) {
    const float4* p = (const float4*)(psum + ((size_t)n * 1600 + i) * 16);
    float acc = 0.f;
#pragma unroll
    for (int qq = 0; qq < 4; ++qq) {
      float4 v = p[qq];
      acc += v.x + v.y + v.z + v.w;
    }
    xm_l[i] = acc * (1.f / 512.f);
  }
  for (int i = tid; i < 512; i += 256) {
    float w = w4[s * 512 + i];
    w4_l[i] = (fabsf(w) > thr) ? w : 0.f;
  }
  for (int i = tid; i < 625; i += 256) ag_l[i] = Ag[s * 625 + i];
  __syncthreads();
  for (int i = tid; i < 400; i += 256) {
    int which = i / 200, idx = i % 200, r = idx / 25, u = idx % 25;
    const float* wrow = (which == 0 ? w1 : w2) + (s * 8 + r) * 64;
    float acc = 0.f;
    for (int cc = 0; cc < 64; ++cc) {
      float w = wrow[cc];
      w = (fabsf(w) > thr) ? w : 0.f;
      acc += w * xm_l[cc * 25 + u];
    }
    acc += (which == 0 ? b1 : b2)[s * 8 + r];
    if (which == 0) x1_l[idx] = acc;
    else x2_l[idx] = acc;
  }
  __syncthreads();
  for (int i = tid; i < 8 * 625; i += 256) {
    int r = i / 625, uv = i % 625, u = uv / 25, v = uv % 25;
    att_l[i] = tanhf(x1_l[r * 25 + u] - x2_l[r * 25 + v]);
  }
  __syncthreads();
  if (tid < 200) {
    int r = tid / 25, v = tid % 25;
    float sum = 0.f;
    for (int u = 0; u < 25; ++u) sum += att_l[r * 625 + u * 25 + v];
    attsum_l[tid] = sum;
  } else if (tid < 225) {
    int v = tid - 200;
    float sum = 0.f;
    for (int u = 0; u < 25; ++u) sum += ag_l[u * 25 + v];
    acs_l[v] = sum;
  }
  __syncthreads();
  const float al = alpha[0];
  // a_ext[c][u][v]: u<25 -> a ; u==25 -> colsum(a) (bias-fold) ; u>25 -> 0
  unsigned char* afrag = ws + WS_AFRAG + (size_t)(s * 16 + n) * 131072;
  for (int slot = q * 2048 + tid; slot < (q + 1) * 2048; slot += 256) {
    int c = slot >> 7, vt = (slot >> 6) & 1, l = slot & 63;
    int v = vt * 16 + (l & 15), g = l >> 4;
    bf16x8 out;
    if (v < 25) {
      float b4v = b4[s * 64 + c];
#pragma unroll
      for (int j = 0; j < 8; ++j) {
        int u = g * 8 + j;
        float val = 0.f;
        if (u < 25) {
          float acc = 0.f;
#pragma unroll
          for (int r = 0; r < 8; ++r) acc += w4_l[c * 8 + r] * att_l[r * 625 + u * 25 + v];
          val = al * (acc + b4v) + ag_l[u * 25 + v];
        } else if (u == 25) {
          float acc = 0.f;
#pragma unroll
          for (int r = 0; r < 8; ++r) acc += w4_l[c * 8 + r] * attsum_l[r * 25 + v];
          val = al * acc + 25.f * al * b4v + acs_l[v];
        }
        out[j] = (__bf16)val;
      }
    } else {
#pragma unroll
      for (int j = 0; j < 8; ++j) out[j] = (__bf16)0.f;
    }
    *(bf16x8*)(afrag + (size_t)slot * 16) = out;
  }
  // w3 frags (B-operand layout [o][c'])
  if (n == 0 && tid < 128) {
    unsigned char* w3f = ws + WS_W3F + (size_t)s * 8192;
    int slot = q * 128 + tid;
    int ot = slot >> 7, ks = (slot >> 6) & 1, l = slot & 63;
    int o = ot * 16 + (l & 15), g = l >> 4;
    bf16x8 out;
#pragma unroll
    for (int j = 0; j < 8; ++j) {
      int cp = ks * 32 + g * 8 + j;
      float w = w3[(s * 64 + o) * 64 + cp];
      out[j] = (__bf16)((fabsf(w) > thr) ? w : 0.f);
    }
    *(bf16x8*)(w3f + slot * 16) = out;
  }
}

// ---- k3: r10 structure; xa from x_tr (b128); w3 in LDS; B2 all-16; f32 residual
__global__ __launch_bounds__(512) void k3_main(const float* __restrict__ x,
                                               const float* __restrict__ b3,
                                               const unsigned char* __restrict__ ws,
                                               float* __restrict__ y) {
  const int n = blockIdx.x;   // linear%8 == n%8 -> same-n blocks share XCD
  const int tb = blockIdx.y;  // 0..31 (16-t chunks)
  extern __shared__ __align__(16) unsigned char smem[];  // 90112
  const int tid = threadIdx.x;
  const int w = tid >> 6, l = tid & 63, g = l >> 4, l15 = l & 15;

  // one-time: copy w3 frags (24 KB) into LDS at 65536
  {
    const f32x4* src = (const f32x4*)(ws + WS_W3F);
    f32x4* dst = (f32x4*)(smem + 65536);
    for (int i = tid; i < 1536; i += 512) dst[i] = src[i];
  }
  // zero X3s pad u=26..31 (3 u32 per (c,t))
  for (int idx = tid; idx < 3072; idx += 512) {
    int pair = idx / 3, k = idx % 3;
    int c = pair >> 4, t = pair & 15;
    *(unsigned int*)(smem + swzB16(c, t, 52 + 4 * k)) = 0u;
  }

  // A-frags from x_tr: one b128 per (cti,kf). col = t_in_tc*25+u.
  const unsigned char* xt = ws + WS_XTR + (size_t)n * 1638400 +
                            (size_t)(tb >> 1) * 102400 + (size_t)(tb & 1) * 51200;
  bf16x8 xa[4][2];
#pragma unroll
  for (int cti = 0; cti < 4; ++cti) {
    int t = 2 * w + (cti >> 1);
    int u = (cti & 1) * 16 + l15;
    if (u < 25) {
      const unsigned char* bp = xt + (size_t)(t * 25 + u) * 128;
      xa[cti][0] = *(const bf16x8*)(bp + g * 16);
      xa[cti][1] = *(const bf16x8*)(bp + 64 + g * 16);
    } else {
#pragma unroll
      for (int j = 0; j < 8; ++j) { xa[cti][0][j] = (__bf16)0.f; xa[cti][1][j] = (__bf16)0.f; }
    }
  }
  __syncthreads();  // w3_lds + pads ready

  const unsigned char* afrag = ws + WS_AFRAG;

  f32x4 zacc[8][2];
#pragma unroll
  for (int cc = 0; cc < 8; ++cc)
#pragma unroll
    for (int vt = 0; vt < 2; ++vt) {
      f32x4 zz = {0.f, 0.f, 0.f, 0.f};
      zacc[cc][vt] = zz;
    }

  for (int s = 0; s < kS; ++s) {
    // B2 all-16 upfront (drained once at the next barrier)
    bf16x8 B2[8][2];
    const unsigned char* af = afrag + (size_t)(s * 16 + n) * 131072;
#pragma unroll
    for (int cc = 0; cc < 8; ++cc) {
      int c = w * 8 + cc;
#pragma unroll
      for (int vt = 0; vt < 2; ++vt)
        B2[cc][vt] = *(const bf16x8*)(af + ((c * 2 + vt) * 64 + l) * 16);
    }
    if (s) __syncthreads();  // GEMM2(s-1) X3s reads done before scatter

    // GEMM1 per o-tile from LDS w3 + xa regs; scatter immediately
    const unsigned char* w3l = smem + 65536 + s * 8192;
#pragma unroll
    for (int ot = 0; ot < 4; ++ot) {
      bf16x8 wk0 = *(const bf16x8*)(w3l + ((ot * 2 + 0) * 64 + l) * 16);
      bf16x8 wk1 = *(const bf16x8*)(w3l + ((ot * 2 + 1) * 64 + l) * 16);
      int c = ot * 16 + l15;
#pragma unroll
      for (int cti = 0; cti < 4; ++cti) {
        f32x4 d = {0.f, 0.f, 0.f, 0.f};
        d = __builtin_amdgcn_mfma_f32_16x16x32_bf16(xa[cti][0], wk0, d, 0, 0, 0);
        d = __builtin_amdgcn_mfma_f32_16x16x32_bf16(xa[cti][1], wk1, d, 0, 0, 0);
        int tt = 2 * w + (cti >> 1);
        if (!(cti & 1)) {  // u = g*4+j
          bf16x4v pk;
          pk[0] = (__bf16)d[0]; pk[1] = (__bf16)d[1];
          pk[2] = (__bf16)d[2]; pk[3] = (__bf16)d[3];
          *(bf16x4v*)(smem + swzB16(c, tt, g * 8)) = pk;
        } else if (g < 2) {  // u = 16+g*4+j
          bf16x4v pk;
          pk[0] = (__bf16)d[0]; pk[1] = (__bf16)d[1];
          pk[2] = (__bf16)d[2]; pk[3] = (__bf16)d[3];
          *(bf16x4v*)(smem + swzB16(c, tt, 32 + g * 8)) = pk;
        } else if (g == 2) {  // u = 24 only
          *(__bf16*)(smem + swzB16(c, tt, 48)) = (__bf16)d[0];
        }
      }
    }
    // bias row u=25
    for (int i = tid; i < 1024; i += 512) {
      int c = i >> 4, t = i & 15;
      *(__bf16*)(smem + swzB16(c, t, 50)) = (__bf16)b3[s * 64 + c];
    }
    __syncthreads();
    // GEMM2: z[t][v] += X3s[c] . a_ext[c]  (per-c batched; M=16 = all t)
#pragma unroll
    for (int cc = 0; cc < 8; ++cc) {
      int c = w * 8 + cc;
      bf16x8 a2 = *(const bf16x8*)(smem + swzB16(c, l15, g * 16));
      zacc[cc][0] = __builtin_amdgcn_mfma_f32_16x16x32_bf16(a2, B2[cc][0], zacc[cc][0], 0, 0, 0);
      zacc[cc][1] = __builtin_amdgcn_mfma_f32_16x16x32_bf16(a2, B2[cc][1], zacc[cc][1], 0, 0, 0);
    }
  }
  __syncthreads();  // all X3s reads done; reuse [0,51200) as zs f32 [32][400]
  float* zs = (float*)smem;
  const float4* xg4 = (const float4*)(x + (size_t)n * kC * kTV);
  float4* yg4 = (float4*)(y + (size_t)n * kC * kTV);
#pragma unroll
  for (int h = 0; h < 2; ++h) {
    if ((w >> 2) == h) {
      int c0l = (w & 3) * 8;
#pragma unroll
      for (int cc = 0; cc < 8; ++cc)
#pragma unroll
        for (int vt = 0; vt < 2; ++vt) {
          int v = vt * 16 + l15;
          if (v < 25) {
#pragma unroll
            for (int jj = 0; jj < 4; ++jj)
              zs[(c0l + cc) * 400 + (g * 4 + jj) * 25 + v] = zacc[cc][vt][jj];
          }
        }
    }
    __syncthreads();
    for (int i4 = tid; i4 < 3200; i4 += 512) {
      int cl = i4 / 100, r4 = i4 % 100, c = h * 32 + cl;
      float4 xv = xg4[c * 3200 + tb * 100 + r4];
      f32x4 zv = *(const f32x4*)(zs + cl * 400 + r4 * 4);
      float4 o;
      o.x = fmaxf(zv[0] + xv.x, 0.f);
      o.y = fmaxf(zv[1] + xv.y, 0.f);
      o.z = fmaxf(zv[2] + xv.z, 0.f);
      o.w = fmaxf(zv[3] + xv.w, 0.f);
      yg4[c * 3200 + tb * 100 + r4] = o;
    }
    __syncthreads();
  }
}

extern "C" void kernel_launch(void* const* d_in, const int* in_sizes, int n_in,
                              void* d_out, int out_size, void* d_ws, size_t ws_size,
                              hipStream_t stream) {
  const float* x = (const float*)d_in[0];
  const float* Ag = (const float*)d_in[1];
  const float* alpha = (const float*)d_in[2];
  const float* w1 = (const float*)d_in[3];
  const float* b1 = (const float*)d_in[4];
  const float* w2 = (const float*)d_in[5];
  const float* b2 = (const float*)d_in[6];
  const float* w3 = (const float*)d_in[7];
  const float* b3 = (const float*)d_in[8];
  const float* w4 = (const float*)d_in[9];
  const float* b4 = (const float*)d_in[10];
  const int* sparse = (const int*)d_in[11];

  unsigned char* ws = (unsigned char*)d_ws;
  float* y = (float*)d_out;

  hipFuncSetAttribute((const void*)k1_tr,
                      hipFuncAttributeMaxDynamicSharedMemorySize, 102400);
  hipFuncSetAttribute((const void*)k3_main,
                      hipFuncAttributeMaxDynamicSharedMemorySize, 90112);

  dim3 g1(kN, kT / 32);
  k1_tr<<<g1, 512, 102400, stream>>>(x, ws);
  k2_attn<<<kS * kN * 4, 256, 0, stream>>>(Ag, alpha, w1, b1, w2, b2, w3, w4,
                                           b4, sparse, ws);
  dim3 g3(kN, kT / 16);
  k3_main<<<g3, 512, 90112, stream>>>(x, b3, ws, y);
}

// Round 16
// 74.328 us; speedup vs baseline: 1.8228x; 1.1625x over previous
//
#include <hip/hip_runtime.h>
#include <cmath>

typedef __bf16 bf16x4v __attribute__((ext_vector_type(4)));
typedef __bf16 bf16x8 __attribute__((ext_vector_type(8)));
typedef float f32x4 __attribute__((ext_vector_type(4)));

namespace {
constexpr int kN = 16, kC = 64, kT = 512, kV = 25, kS = 3, kO = 64;
constexpr int kTV = kT * kV;  // 12800
// ws layout (bytes): xm f32[25600 f] | afrag[48][8192][16] | w3f[3][512][16] | x_bf bf16
constexpr size_t WS_AFRAG = 102400;
constexpr size_t WS_W3F = WS_AFRAG + (size_t)48 * 131072;  // 6,393,856
constexpr size_t WS_XBF = WS_W3F + 3 * 8192;               // 6,418,432
}  // namespace

// X3s: bf16 [c 64][t 16][u 32] swizzled with ((c^t)&7)<<4 (XOR bits 4-6 ONLY:
// >= 16-byte read granule). Bytes [0, 65536). w3_lds (8KB, current s) at 65536.
__device__ __forceinline__ int swzB16(int c, int t, int ubyte) {
  return (c << 10) + (((t << 6) + ubyte) ^ ((((c ^ t) & 7)) << 4));
}

// ---- k1: stream x f32 -> x_bf bf16 (natural layout) + mean via phase classes
__global__ __launch_bounds__(256) void k1_cvt(const float* __restrict__ x,
                                              __bf16* __restrict__ xbf,
                                              float* __restrict__ xm) {
  const int bid = blockIdx.x;  // n*64 + c
  __shared__ float part[250][4];
  const int tid = threadIdx.x;
  const float4* xg4 = (const float4*)(x + (size_t)bid * kTV);
  bf16x4v* xb4 = (bf16x4v*)(xbf + (size_t)bid * kTV);
  if (tid < 250) {
    float a0 = 0.f, a1 = 0.f, a2 = 0.f, a3 = 0.f;
    for (int j = tid; j < 3200; j += 250) {  // j%250==tid -> const v-phase
      float4 v = xg4[j];
      a0 += v.x; a1 += v.y; a2 += v.z; a3 += v.w;
      bf16x4v o;
      o[0] = (__bf16)v.x; o[1] = (__bf16)v.y;
      o[2] = (__bf16)v.z; o[3] = (__bf16)v.w;
      xb4[j] = o;
    }
    part[tid][0] = a0; part[tid][1] = a1; part[tid][2] = a2; part[tid][3] = a3;
  }
  __syncthreads();
  if (tid < 25) {
    float s = 0.f;
#pragma unroll
    for (int r = 0; r < 4; ++r) {
      int q = ((tid - r + 25) % 25) * 19 % 25;
#pragma unroll
      for (int p = 0; p < 10; ++p) s += part[q + 25 * p][r];
    }
    xm[bid * 25 + tid] = s * (1.f / 512.f);
  }
}

// ---- k2: a_frag (bf16, MFMA-B order, bias/colsum folded) + w3 frags
__global__ __launch_bounds__(256) void k2_attn(
    const float* __restrict__ xm, const float* __restrict__ Ag,
    const float* __restrict__ alpha, const float* __restrict__ w1,
    const float* __restrict__ b1, const float* __restrict__ w2,
    const float* __restrict__ b2, const float* __restrict__ w3,
    const float* __restrict__ w4, const float* __restrict__ b4,
    const int* __restrict__ sparse, unsigned char* __restrict__ ws) {
  const float thr = (float)sparse[0];
  const int b = blockIdx.x;
  const int s = b >> 6, n = (b >> 2) & 15, q = b & 3;
  __shared__ float xm_l[1600];
  __shared__ float x1_l[200], x2_l[200];
  __shared__ float att_l[8 * 625];
  __shared__ float attsum_l[200];
  __shared__ float ag_l[625];
  __shared__ float acs_l[25];
  __shared__ float w4_l[512];
  const int tid = threadIdx.x;
  for (int i = tid; i < 1600; i += 256) xm_l[i] = xm[n * 1600 + i];
  for (int i = tid; i < 512; i += 256) {
    float w = w4[s * 512 + i];
    w4_l[i] = (fabsf(w) > thr) ? w : 0.f;
  }
  for (int i = tid; i < 625; i += 256) ag_l[i] = Ag[s * 625 + i];
  __syncthreads();
  for (int i = tid; i < 400; i += 256) {
    int which = i / 200, idx = i % 200, r = idx / 25, u = idx % 25;
    const float* wrow = (which == 0 ? w1 : w2) + (s * 8 + r) * 64;
    float acc = 0.f;
    for (int cc = 0; cc < 64; ++cc) {
      float w = wrow[cc];
      w = (fabsf(w) > thr) ? w : 0.f;
      acc += w * xm_l[cc * 25 + u];
    }
    acc += (which == 0 ? b1 : b2)[s * 8 + r];
    if (which == 0) x1_l[idx] = acc;
    else x2_l[idx] = acc;
  }
  __syncthreads();
  for (int i = tid; i < 8 * 625; i += 256) {
    int r = i / 625, uv = i % 625, u = uv / 25, v = uv % 25;
    att_l[i] = tanhf(x1_l[r * 25 + u] - x2_l[r * 25 + v]);
  }
  __syncthreads();
  if (tid < 200) {
    int r = tid / 25, v = tid % 25;
    float sum = 0.f;
    for (int u = 0; u < 25; ++u) sum += att_l[r * 625 + u * 25 + v];
    attsum_l[tid] = sum;
  } else if (tid < 225) {
    int v = tid - 200;
    float sum = 0.f;
    for (int u = 0; u < 25; ++u) sum += ag_l[u * 25 + v];
    acs_l[v] = sum;
  }
  __syncthreads();
  const float al = alpha[0];
  // a_ext[c][u][v]: u<25 -> a ; u==25 -> colsum(a) (bias-fold) ; u>25 -> 0
  unsigned char* afrag = ws + WS_AFRAG + (size_t)(s * 16 + n) * 131072;
  for (int slot = q * 2048 + tid; slot < (q + 1) * 2048; slot += 256) {
    int c = slot >> 7, vt = (slot >> 6) & 1, l = slot & 63;
    int v = vt * 16 + (l & 15), g = l >> 4;
    bf16x8 out;
    if (v < 25) {
      float b4v = b4[s * 64 + c];
#pragma unroll
      for (int j = 0; j < 8; ++j) {
        int u = g * 8 + j;
        float val = 0.f;
        if (u < 25) {
          float acc = 0.f;
#pragma unroll
          for (int r = 0; r < 8; ++r) acc += w4_l[c * 8 + r] * att_l[r * 625 + u * 25 + v];
          val = al * (acc + b4v) + ag_l[u * 25 + v];
        } else if (u == 25) {
          float acc = 0.f;
#pragma unroll
          for (int r = 0; r < 8; ++r) acc += w4_l[c * 8 + r] * attsum_l[r * 25 + v];
          val = al * acc + 25.f * al * b4v + acs_l[v];
        }
        out[j] = (__bf16)val;
      }
    } else {
#pragma unroll
      for (int j = 0; j < 8; ++j) out[j] = (__bf16)0.f;
    }
    *(bf16x8*)(afrag + (size_t)slot * 16) = out;
  }
  // w3 frags (B-operand layout [o][c'])
  if (n == 0 && tid < 128) {
    unsigned char* w3f = ws + WS_W3F + (size_t)s * 8192;
    int slot = q * 128 + tid;
    int ot = slot >> 7, ks = (slot >> 6) & 1, l = slot & 63;
    int o = ot * 16 + (l & 15), g = l >> 4;
    bf16x8 out;
#pragma unroll
    for (int j = 0; j < 8; ++j) {
      int cp = ks * 32 + g * 8 + j;
      float w = w3[(s * 64 + o) * 64 + cp];
      out[j] = (__bf16)((fabsf(w) > thr) ? w : 0.f);
    }
    *(bf16x8*)(w3f + slot * 16) = out;
  }
}

// ---- k3: r10 structure; LDS 72KB (X3s 64K + w3-of-current-s 8K) -> 2 blocks/CU
__global__ __launch_bounds__(512) void k3_main(const __bf16* __restrict__ xbf,
                                               const float* __restrict__ b3,
                                               const unsigned char* __restrict__ ws,
                                               float* __restrict__ y) {
  const int n = blockIdx.x;   // linear%8 == n%8 -> same-n blocks share XCD
  const int tb = blockIdx.y;  // 0..31 (16-t chunks)
  extern __shared__ __align__(16) unsigned char smem[];  // 73728
  const int tid = threadIdx.x;
  const int w = tid >> 6, l = tid & 63, g = l >> 4, l15 = l & 15;

  // zero X3s pad u=26..31 (3 u32 per (c,t)); visible via the s=0 barrier
  for (int idx = tid; idx < 3072; idx += 512) {
    int pair = idx / 3, k = idx % 3;
    int c = pair >> 4, t = pair & 15;
    *(unsigned int*)(smem + swzB16(c, t, 52 + 4 * k)) = 0u;
  }

  // A-frags of X from x_bf: lane m=u, k=c'; t = 2w+(cti>>1). s-invariant.
  bf16x8 xa[4][2];
#pragma unroll
  for (int cti = 0; cti < 4; ++cti)
#pragma unroll
    for (int kf = 0; kf < 2; ++kf)
#pragma unroll
      for (int j = 0; j < 8; ++j) xa[cti][kf][j] = (__bf16)0.f;
  {
    const __bf16* xbp = xbf + (size_t)n * kC * kTV;
#pragma unroll
    for (int cti = 0; cti < 4; ++cti) {
      int tt = tb * 16 + 2 * w + (cti >> 1);
      int u = (cti & 1) * 16 + l15;
      if (u < 25) {
#pragma unroll
        for (int kf = 0; kf < 2; ++kf)
#pragma unroll
          for (int j = 0; j < 8; ++j) {
            int cp = kf * 32 + g * 8 + j;
            xa[cti][kf][j] = xbp[(size_t)cp * kTV + tt * 25 + u];
          }
      }
    }
  }

  const unsigned char* afrag = ws + WS_AFRAG;
  const unsigned char* w3f = ws + WS_W3F;

  f32x4 zacc[8][2];
#pragma unroll
  for (int cc = 0; cc < 8; ++cc)
#pragma unroll
    for (int vt = 0; vt < 2; ++vt) {
      f32x4 zz = {0.f, 0.f, 0.f, 0.f};
      zacc[cc][vt] = zz;
    }

  for (int s = 0; s < kS; ++s) {
    // B2 all-16 upfront (drained once at the next barrier)
    bf16x8 B2[8][2];
    const unsigned char* af = afrag + (size_t)(s * 16 + n) * 131072;
#pragma unroll
    for (int cc = 0; cc < 8; ++cc) {
      int c = w * 8 + cc;
#pragma unroll
      for (int vt = 0; vt < 2; ++vt)
        B2[cc][vt] = *(const bf16x8*)(af + ((c * 2 + vt) * 64 + l) * 16);
    }
    // stage this s's w3 frags (8KB) into LDS; barrier also orders prev GEMM2
    ((f32x4*)(smem + 65536))[tid] =
        ((const f32x4*)(w3f + (size_t)s * 8192))[tid];
    __syncthreads();

    // GEMM1 per o-tile from LDS w3 + xa regs; scatter immediately
    const unsigned char* w3l = smem + 65536;
#pragma unroll
    for (int ot = 0; ot < 4; ++ot) {
      bf16x8 wk0 = *(const bf16x8*)(w3l + ((ot * 2 + 0) * 64 + l) * 16);
      bf16x8 wk1 = *(const bf16x8*)(w3l + ((ot * 2 + 1) * 64 + l) * 16);
      int c = ot * 16 + l15;
#pragma unroll
      for (int cti = 0; cti < 4; ++cti) {
        f32x4 d = {0.f, 0.f, 0.f, 0.f};
        d = __builtin_amdgcn_mfma_f32_16x16x32_bf16(xa[cti][0], wk0, d, 0, 0, 0);
        d = __builtin_amdgcn_mfma_f32_16x16x32_bf16(xa[cti][1], wk1, d, 0, 0, 0);
        int tt = 2 * w + (cti >> 1);
        if (!(cti & 1)) {  // u = g*4+j
          bf16x4v pk;
          pk[0] = (__bf16)d[0]; pk[1] = (__bf16)d[1];
          pk[2] = (__bf16)d[2]; pk[3] = (__bf16)d[3];
          *(bf16x4v*)(smem + swzB16(c, tt, g * 8)) = pk;
        } else if (g < 2) {  // u = 16+g*4+j
          bf16x4v pk;
          pk[0] = (__bf16)d[0]; pk[1] = (__bf16)d[1];
          pk[2] = (__bf16)d[2]; pk[3] = (__bf16)d[3];
          *(bf16x4v*)(smem + swzB16(c, tt, 32 + g * 8)) = pk;
        } else if (g == 2) {  // u = 24 only
          *(__bf16*)(smem + swzB16(c, tt, 48)) = (__bf16)d[0];
        }
      }
    }
    // bias row u=25
    for (int i = tid; i < 1024; i += 512) {
      int c = i >> 4, t = i & 15;
      *(__bf16*)(smem + swzB16(c, t, 50)) = (__bf16)b3[s * 64 + c];
    }
    __syncthreads();
    // GEMM2: z[t][v] += X3s[c] . a_ext[c]  (per-c batched; M=16 = all t)
#pragma unroll
    for (int cc = 0; cc < 8; ++cc) {
      int c = w * 8 + cc;
      bf16x8 a2 = *(const bf16x8*)(smem + swzB16(c, l15, g * 16));
      zacc[cc][0] = __builtin_amdgcn_mfma_f32_16x16x32_bf16(a2, B2[cc][0], zacc[cc][0], 0, 0, 0);
      zacc[cc][1] = __builtin_amdgcn_mfma_f32_16x16x32_bf16(a2, B2[cc][1], zacc[cc][1], 0, 0, 0);
    }
  }
  __syncthreads();  // all X3s reads done; reuse [0,51200) as zs f32 [32][400]
  float* zs = (float*)smem;
  const __bf16* xbp = xbf + (size_t)n * kC * kTV;
  float4* yg4 = (float4*)(y + (size_t)n * kC * kTV);
#pragma unroll
  for (int h = 0; h < 2; ++h) {
    if ((w >> 2) == h) {
      int c0l = (w & 3) * 8;
#pragma unroll
      for (int cc = 0; cc < 8; ++cc)
#pragma unroll
        for (int vt = 0; vt < 2; ++vt) {
          int v = vt * 16 + l15;
          if (v < 25) {
#pragma unroll
            for (int jj = 0; jj < 4; ++jj)
              zs[(c0l + cc) * 400 + (g * 4 + jj) * 25 + v] = zacc[cc][vt][jj];
          }
        }
    }
    __syncthreads();
    for (int i4 = tid; i4 < 3200; i4 += 512) {
      int cl = i4 / 100, r4 = i4 % 100, c = h * 32 + cl;
      bf16x4v xv = *(const bf16x4v*)(xbp + (size_t)c * kTV + tb * 400 + r4 * 4);
      f32x4 zv = *(const f32x4*)(zs + cl * 400 + r4 * 4);
      float4 o;
      o.x = fmaxf(zv[0] + (float)xv[0], 0.f);
      o.y = fmaxf(zv[1] + (float)xv[1], 0.f);
      o.z = fmaxf(zv[2] + (float)xv[2], 0.f);
      o.w = fmaxf(zv[3] + (float)xv[3], 0.f);
      yg4[c * 3200 + tb * 100 + r4] = o;
    }
    __syncthreads();
  }
}

extern "C" void kernel_launch(void* const* d_in, const int* in_sizes, int n_in,
                              void* d_out, int out_size, void* d_ws, size_t ws_size,
                              hipStream_t stream) {
  const float* x = (const float*)d_in[0];
  const float* Ag = (const float*)d_in[1];
  const float* alpha = (const float*)d_in[2];
  const float* w1 = (const float*)d_in[3];
  const float* b1 = (const float*)d_in[4];
  const float* w2 = (const float*)d_in[5];
  const float* b2 = (const float*)d_in[6];
  const float* w3 = (const float*)d_in[7];
  const float* b3 = (const float*)d_in[8];
  const float* w4 = (const float*)d_in[9];
  const float* b4 = (const float*)d_in[10];
  const int* sparse = (const int*)d_in[11];

  unsigned char* ws = (unsigned char*)d_ws;
  float* xm = (float*)ws;  // [16][64][25] f32 at offset 0
  __bf16* xbf = (__bf16*)(ws + WS_XBF);
  float* y = (float*)d_out;

  hipFuncSetAttribute((const void*)k3_main,
                      hipFuncAttributeMaxDynamicSharedMemorySize, 73728);

  k1_cvt<<<kN * kC, 256, 0, stream>>>(x, xbf, xm);
  k2_attn<<<kS * kN * 4, 256, 0, stream>>>(xm, Ag, alpha, w1, b1, w2, b2, w3, w4,
                                           b4, sparse, ws);
  dim3 g3(kN, kT / 16);
  k3_main<<<g3, 512, 73728, stream>>>(xbf, b3, ws, y);
}